// Round 7
// baseline (423.663 us; speedup 1.0000x reference)
//
#include <hip/hip_runtime.h>

#define NROWS 4096
#define DDIM  128
#define NHEAD 8

typedef __attribute__((ext_vector_type(8))) short short8;
typedef __attribute__((ext_vector_type(4))) float floatx4;

__device__ __forceinline__ float bf2f(unsigned short u){
  unsigned v = ((unsigned)u) << 16;
  return __builtin_bit_cast(float, v);
}
__device__ __forceinline__ unsigned short f2bf(float f){
  unsigned u = __builtin_bit_cast(unsigned, f);
  u += 0x7FFFu + ((u >> 16) & 1u);
  return (unsigned short)(u >> 16);
}
__device__ __forceinline__ void split2(float v, unsigned short& hi, unsigned short& lo){
  hi = f2bf(v);
  lo = f2bf(v - bf2f(hi));
}

// fp32 sentinels: 500=ws too small, 1000=in_sizes mismatch, 2000=launch fail.
__global__ void fill_kernel(float* __restrict__ out, float val, int n){
  int i = blockIdx.x * 256 + threadIdx.x;
  if (i < n) out[i] = val;
}
__global__ void zero_kernel(float* __restrict__ p, int n){
  int i = blockIdx.x * 256 + threadIdx.x;
  if (i < n) p[i] = 0.f;
}

// ---------------------------------------------------------------------------
// Kernel 1: k = x@Wk[h] (bf16 hi/lo pair), v = x@Wv[h] (bf16, pre-transposed
// vt[h][tile][d][key&63]). 3-term bf16 MFMA from fp32 inputs.
// grid (64 row-tiles, NHEAD, z: 0=k 1=v), block 256.
// ---------------------------------------------------------------------------
__global__ __launch_bounds__(256, 2) void proj_kernel(
    const float* __restrict__ x,
    const float* __restrict__ Wk, const float* __restrict__ Wv,
    unsigned short* __restrict__ khi, unsigned short* __restrict__ klo,
    unsigned short* __restrict__ vt)
{
  __shared__ alignas(16) unsigned short wthi[DDIM][72];
  __shared__ alignas(16) unsigned short wtlo[DDIM][72];
  const int tid = threadIdx.x, lane = tid & 63, wave = tid >> 6;
  const int l4 = lane & 15, quad = lane >> 4;
  const int tile = blockIdx.x, h = blockIdx.y, z = blockIdx.z;
  const float* W = (z == 0 ? Wk : Wv) + h * DDIM * DDIM;

  floatx4 acc[8];
#pragma unroll
  for (int c = 0; c < 8; c++) acc[c] = (floatx4)0.f;

  for (int fh = 0; fh < 2; fh++) {
    // stage W^T chunk (hi/lo bf16) : wt[d][f_local], f = fh*64 + f_local
    for (int i = tid; i < DDIM * 64; i += 256) {
      const int d = i >> 6, fl = i & 63;
      unsigned short hi, lo;
      split2(W[(fh * 64 + fl) * DDIM + d], hi, lo);
      wthi[d][fl] = hi; wtlo[d][fl] = lo;
    }
    __syncthreads();

    // x A-frags (fp32 global -> hi/lo bf16)
    const float* xr = x + (size_t)(tile * 64 + wave * 16 + l4) * DDIM + fh * 64 + quad * 8;
    short8 ah[2], al[2];
#pragma unroll
    for (int t2 = 0; t2 < 2; t2++) {
      float4 v0 = *(const float4*)(xr + t2 * 32);
      float4 v1 = *(const float4*)(xr + t2 * 32 + 4);
      float xv[8] = {v0.x, v0.y, v0.z, v0.w, v1.x, v1.y, v1.z, v1.w};
#pragma unroll
      for (int j = 0; j < 8; j++) {
        unsigned short hi, lo; split2(xv[j], hi, lo);
        ah[t2][j] = (short)hi; al[t2][j] = (short)lo;
      }
    }
#pragma unroll
    for (int t2 = 0; t2 < 2; t2++) {
#pragma unroll
      for (int c = 0; c < 8; c++) {
        short8 bh = *(const short8*)(&wthi[c * 16 + l4][t2 * 32 + quad * 8]);
        short8 bl = *(const short8*)(&wtlo[c * 16 + l4][t2 * 32 + quad * 8]);
        acc[c] = __builtin_amdgcn_mfma_f32_16x16x32_bf16(ah[t2], bh, acc[c], 0, 0, 0);
        acc[c] = __builtin_amdgcn_mfma_f32_16x16x32_bf16(al[t2], bh, acc[c], 0, 0, 0);
        acc[c] = __builtin_amdgcn_mfma_f32_16x16x32_bf16(ah[t2], bl, acc[c], 0, 0, 0);
      }
    }
    __syncthreads();
  }

  const int rb = wave * 16 + quad * 4;
#pragma unroll
  for (int c = 0; c < 8; c++) {
    const int d = c * 16 + l4;
#pragma unroll
    for (int r = 0; r < 4; r++) {
      const int n = tile * 64 + rb + r;
      const float val = acc[c][r];
      if (z == 0) {
        unsigned short hi, lo; split2(val, hi, lo);
        const size_t idx = ((size_t)h * NROWS + n) * DDIM + d;
        khi[idx] = hi; klo[idx] = lo;
      } else {
        vt[(((size_t)(h * 64 + tile) * DDIM + d) << 6) + (size_t)(rb + r)] = f2bf(val);
      }
    }
  }
}

// ---------------------------------------------------------------------------
// Kernel 2: flash attention. grid 512 = 8 heads x 64 q-tiles (64 rows).
// Phase 1 computes q in-block (3-term bf16 MFMA from fp32 x,Wq).
// kt loop: 3-term S, per-wave register softmax, P via LDS, PV bf16.
// Output: atomicAdd (fp32) of Wm[h]/l-scaled O into u. LDS union = 62464 B.
// ---------------------------------------------------------------------------
union FlashLds {
  struct { unsigned short hi[DDIM][72], lo[DDIM][72]; } wq;      // 36864 B
  float qf[64][132];                                             // 33792 B
  struct {
    unsigned short khi[64][136], klo[64][136];                   // 34816 B
    unsigned short vt[DDIM][72];                                 // 18432 B
    unsigned short p[4][16][72];                                 //  9216 B
  } kv;                                                          // 62464 B
};

__global__ __launch_bounds__(256, 2) void flash_kernel(
    const float* __restrict__ x, const float* __restrict__ Wq,
    const unsigned short* __restrict__ khi, const unsigned short* __restrict__ klo,
    const unsigned short* __restrict__ vt, const float* __restrict__ Wm,
    float* __restrict__ u)
{
  __shared__ alignas(16) FlashLds lds;
  const int tid = threadIdx.x, lane = tid & 63, wave = tid >> 6;
  const int l4 = lane & 15, quad = lane >> 4;
  const int h = blockIdx.x >> 6, qt = blockIdx.x & 63;
  const int q0 = qt * 64;

  // ---- phase 1: q = x @ Wq[h] for this block's 64 rows ----
  floatx4 qacc[8];
#pragma unroll
  for (int c = 0; c < 8; c++) qacc[c] = (floatx4)0.f;
  {
    const float* Wqh = Wq + h * DDIM * DDIM;
    for (int fh = 0; fh < 2; fh++) {
      for (int i = tid; i < DDIM * 64; i += 256) {
        const int d = i >> 6, fl = i & 63;
        unsigned short hi, lo;
        split2(Wqh[(fh * 64 + fl) * DDIM + d], hi, lo);
        lds.wq.hi[d][fl] = hi; lds.wq.lo[d][fl] = lo;
      }
      __syncthreads();
      const float* xr = x + (size_t)(q0 + wave * 16 + l4) * DDIM + fh * 64 + quad * 8;
      short8 ah[2], al[2];
#pragma unroll
      for (int t2 = 0; t2 < 2; t2++) {
        float4 v0 = *(const float4*)(xr + t2 * 32);
        float4 v1 = *(const float4*)(xr + t2 * 32 + 4);
        float xv[8] = {v0.x, v0.y, v0.z, v0.w, v1.x, v1.y, v1.z, v1.w};
#pragma unroll
        for (int j = 0; j < 8; j++) {
          unsigned short hi, lo; split2(xv[j], hi, lo);
          ah[t2][j] = (short)hi; al[t2][j] = (short)lo;
        }
      }
#pragma unroll
      for (int t2 = 0; t2 < 2; t2++) {
#pragma unroll
        for (int c = 0; c < 8; c++) {
          short8 bh = *(const short8*)(&lds.wq.hi[c * 16 + l4][t2 * 32 + quad * 8]);
          short8 bl = *(const short8*)(&lds.wq.lo[c * 16 + l4][t2 * 32 + quad * 8]);
          qacc[c] = __builtin_amdgcn_mfma_f32_16x16x32_bf16(ah[t2], bh, qacc[c], 0, 0, 0);
          qacc[c] = __builtin_amdgcn_mfma_f32_16x16x32_bf16(al[t2], bh, qacc[c], 0, 0, 0);
          qacc[c] = __builtin_amdgcn_mfma_f32_16x16x32_bf16(ah[t2], bl, qacc[c], 0, 0, 0);
        }
      }
      __syncthreads();
    }
  }
  // q: C-layout -> LDS fp32 -> A-frags (hi/lo bf16)
#pragma unroll
  for (int c = 0; c < 8; c++)
#pragma unroll
    for (int r = 0; r < 4; r++)
      lds.qf[wave * 16 + quad * 4 + r][c * 16 + l4] = qacc[c][r];
  __syncthreads();
  short8 aqh[4], aql[4];
#pragma unroll
  for (int t = 0; t < 4; t++) {
    float4 v0 = *(const float4*)(&lds.qf[wave * 16 + l4][t * 32 + quad * 8]);
    float4 v1 = *(const float4*)(&lds.qf[wave * 16 + l4][t * 32 + quad * 8 + 4]);
    float qv[8] = {v0.x, v0.y, v0.z, v0.w, v1.x, v1.y, v1.z, v1.w};
#pragma unroll
    for (int j = 0; j < 8; j++) {
      unsigned short hi, lo; split2(qv[j], hi, lo);
      aqh[t][j] = (short)hi; aql[t][j] = (short)lo;
    }
  }
  __syncthreads();  // qf reads done; kt staging may overwrite

  // ---- kt loop ----
  float m_run[4], l_run[4];
#pragma unroll
  for (int r = 0; r < 4; r++) { m_run[r] = -1e30f; l_run[r] = 0.f; }
  floatx4 Oacc[8];
#pragma unroll
  for (int c = 0; c < 8; c++) Oacc[c] = (floatx4)0.f;

  const unsigned short* khh = khi + (size_t)h * NROWS * DDIM;
  const unsigned short* klh = klo + (size_t)h * NROWS * DDIM;
  const unsigned short* vth = vt + (size_t)h * 64 * DDIM * 64;

  for (int kt = 0; kt < 64; ++kt) {
    {
      const size_t base = (size_t)kt * 64 * DDIM;
#pragma unroll
      for (int i = tid; i < 64 * 16; i += 256) {
        int r = i >> 4, c8 = (i & 15) * 8;
        *(short8*)(&lds.kv.khi[r][c8]) = *(const short8*)(khh + base + r * DDIM + c8);
        *(short8*)(&lds.kv.klo[r][c8]) = *(const short8*)(klh + base + r * DDIM + c8);
      }
      const unsigned short* vsrc = vth + (size_t)kt * DDIM * 64;
#pragma unroll
      for (int i = tid; i < DDIM * 8; i += 256) {
        int r = i >> 3, c8 = (i & 7) * 8;
        *(short8*)(&lds.kv.vt[r][c8]) = *(const short8*)(vsrc + r * 64 + c8);
      }
    }
    __syncthreads();  // b1: tiles staged

    // S = (qh+ql)(kh+kl)^T, 3-term
    floatx4 Sf[4];
#pragma unroll
    for (int c = 0; c < 4; c++) Sf[c] = (floatx4)0.f;
#pragma unroll
    for (int t = 0; t < 4; t++) {
      short8 bh[4], bl[4];
#pragma unroll
      for (int c = 0; c < 4; c++) {
        bh[c] = *(const short8*)(&lds.kv.khi[c * 16 + l4][t * 32 + quad * 8]);
        bl[c] = *(const short8*)(&lds.kv.klo[c * 16 + l4][t * 32 + quad * 8]);
      }
#pragma unroll
      for (int c = 0; c < 4; c++)
        Sf[c] = __builtin_amdgcn_mfma_f32_16x16x32_bf16(aqh[t], bh[c], Sf[c], 0, 0, 0);
#pragma unroll
      for (int c = 0; c < 4; c++)
        Sf[c] = __builtin_amdgcn_mfma_f32_16x16x32_bf16(aql[t], bh[c], Sf[c], 0, 0, 0);
#pragma unroll
      for (int c = 0; c < 4; c++)
        Sf[c] = __builtin_amdgcn_mfma_f32_16x16x32_bf16(aqh[t], bl[c], Sf[c], 0, 0, 0);
    }

    // per-wave register softmax (lane: row=quad*4+r, key=c*16+l4)
    float mt[4];
#pragma unroll
    for (int r = 0; r < 4; r++)
      mt[r] = fmaxf(fmaxf(Sf[0][r], Sf[1][r]), fmaxf(Sf[2][r], Sf[3][r]));
#pragma unroll
    for (int mk = 1; mk <= 8; mk <<= 1)
#pragma unroll
      for (int r = 0; r < 4; r++) mt[r] = fmaxf(mt[r], __shfl_xor(mt[r], mk, 64));

    float alpha[4];
#pragma unroll
    for (int r = 0; r < 4; r++) {
      const float mn = fmaxf(m_run[r], mt[r]);
      alpha[r] = __expf(m_run[r] - mn);
      m_run[r] = mn;
    }
    float pf[4][4], lsum[4];
#pragma unroll
    for (int r = 0; r < 4; r++) {
#pragma unroll
      for (int c = 0; c < 4; c++) pf[c][r] = __expf(Sf[c][r] - m_run[r]);
      lsum[r] = (pf[0][r] + pf[1][r]) + (pf[2][r] + pf[3][r]);
    }
#pragma unroll
    for (int mk = 1; mk <= 8; mk <<= 1)
#pragma unroll
      for (int r = 0; r < 4; r++) lsum[r] += __shfl_xor(lsum[r], mk, 64);
#pragma unroll
    for (int r = 0; r < 4; r++) l_run[r] = l_run[r] * alpha[r] + lsum[r];

    // P: C-layout -> A-layout via wave-private LDS
#pragma unroll
    for (int c = 0; c < 4; c++)
#pragma unroll
      for (int r = 0; r < 4; r++)
        lds.kv.p[wave][quad * 4 + r][c * 16 + l4] = f2bf(pf[c][r]);
    __syncthreads();  // b2: P visible

    // rescale O, then O += P @ V
#pragma unroll
    for (int c = 0; c < 8; c++) {
      Oacc[c][0] *= alpha[0]; Oacc[c][1] *= alpha[1];
      Oacc[c][2] *= alpha[2]; Oacc[c][3] *= alpha[3];
    }
#pragma unroll
    for (int t = 0; t < 2; t++) {
      short8 ap = *(const short8*)(&lds.kv.p[wave][l4][t * 32 + quad * 8]);
#pragma unroll
      for (int c = 0; c < 8; c++) {
        short8 bv = *(const short8*)(&lds.kv.vt[c * 16 + l4][t * 32 + quad * 8]);
        Oacc[c] = __builtin_amdgcn_mfma_f32_16x16x32_bf16(ap, bv, Oacc[c], 0, 0, 0);
      }
    }
    __syncthreads();  // b3: reads done -> safe to restage
  }

  // epilogue: u[n][d] += Wm[h] * O / l  (fp32 atomics)
  {
    const float wmf = Wm[h];
    float inv[4];
#pragma unroll
    for (int r = 0; r < 4; r++) inv[r] = wmf / l_run[r];
    const int rbase = wave * 16 + quad * 4;
#pragma unroll
    for (int c = 0; c < 8; c++) {
      const int col = c * 16 + l4;
#pragma unroll
      for (int r = 0; r < 4; r++)
        atomicAdd(&u[(size_t)(q0 + rbase + r) * DDIM + col], Oacc[c][r] * inv[r]);
    }
  }
}

// ---------------------------------------------------------------------------
// Kernel 3: y = x + relu((x+u) @ Wg^T + bg), fp32 VALU. grid 2048 x 256.
// ---------------------------------------------------------------------------
__global__ __launch_bounds__(256) void mlp_kernel(
    const float* __restrict__ x, const float* __restrict__ u,
    const float* __restrict__ Wg, const float* __restrict__ bg,
    float* __restrict__ out)
{
  __shared__ float h_s[2][DDIM];
  const int t = threadIdx.x, i = t & 127, r = t >> 7;
  const int n = blockIdx.x * 2 + r;
  h_s[r][i] = x[(size_t)n * DDIM + i] + u[(size_t)n * DDIM + i];
  __syncthreads();
  float g = 0.f;
  for (int j = 0; j < DDIM; j++)
    g += h_s[r][j] * Wg[i * DDIM + j];
  out[(size_t)n * DDIM + i] = x[(size_t)n * DDIM + i] + fmaxf(g + bg[i], 0.f);
}

extern "C" void kernel_launch(void* const* d_in, const int* in_sizes, int n_in,
                              void* d_out, int out_size, void* d_ws, size_t ws_size,
                              hipStream_t stream) {
  float* out = (float*)d_out;
  const int fill_blocks = (out_size + 255) / 256;

  const bool ok_sizes =
      n_in == 7 &&
      in_sizes[0] == NROWS * DDIM &&
      in_sizes[1] == NHEAD * DDIM * DDIM &&
      in_sizes[2] == NHEAD * DDIM * DDIM &&
      in_sizes[3] == NHEAD * DDIM * DDIM &&
      in_sizes[4] == NHEAD &&
      in_sizes[5] == DDIM * DDIM &&
      in_sizes[6] == DDIM &&
      out_size == NROWS * DDIM;
  if (!ok_sizes) {
    fill_kernel<<<fill_blocks, 256, 0, stream>>>(out, 1000.f, out_size);
    return;
  }

  // ws: u fp32 (2MB) + khi/klo/vt bf16 (3 x 8.39MB) = 27.2MB (proven budget)
  const size_t HND = (size_t)NHEAD * NROWS * DDIM;
  const size_t need = (size_t)NROWS * DDIM * 4 + 3 * HND * 2;
  if (ws_size < need) {
    fill_kernel<<<fill_blocks, 256, 0, stream>>>(out, 500.f, out_size);
    return;
  }

  const float* x  = (const float*)d_in[0];
  const float* Wk = (const float*)d_in[1];
  const float* Wq = (const float*)d_in[2];
  const float* Wv = (const float*)d_in[3];
  const float* Wm = (const float*)d_in[4];
  const float* Wg = (const float*)d_in[5];
  const float* bg = (const float*)d_in[6];

  float*          u   = (float*)d_ws;
  unsigned short* khi = (unsigned short*)(u + (size_t)NROWS * DDIM);
  unsigned short* klo = khi + HND;
  unsigned short* vt  = klo + HND;

  (void)hipGetLastError();
  zero_kernel<<<dim3(2048), 256, 0, stream>>>(u, NROWS * DDIM);
  proj_kernel<<<dim3(64, NHEAD, 2), 256, 0, stream>>>(x, Wk, Wv, khi, klo, vt);
  flash_kernel<<<dim3(512), 256, 0, stream>>>(x, Wq, khi, klo, vt, Wm, u);
  mlp_kernel<<<dim3(2048), 256, 0, stream>>>(x, u, Wg, bg, out);
  if (hipGetLastError() != hipSuccess) {
    fill_kernel<<<fill_blocks, 256, 0, stream>>>(out, 2000.f, out_size);
  }
}